// Round 8
// baseline (52.879 us; speedup 1.0000x reference)
//
#include <hip/hip_runtime.h>

// B=512 batches, MBS=32768 samples, F=512 taps, CD=16 cond dims.
// y[b,n] = sum_{t<512} h[b,t] * x[b,n-t]  (linear conv, zero history)

typedef float f32x16 __attribute__((ext_vector_type(16)));
typedef float f32x4  __attribute__((ext_vector_type(4)));
typedef __bf16 bf16x8 __attribute__((ext_vector_type(8)));

__device__ __forceinline__ unsigned short f2bf(float f) {
    unsigned int u = __float_as_uint(f);
    u += 0x7FFFu + ((u >> 16) & 1u);   // round-to-nearest-even
    return (unsigned short)(u >> 16);
}

__device__ __forceinline__ uint4 pack8n(float4 a, float4 b) {
    bf16x8 v;
    v[0] = (__bf16)a.x; v[1] = (__bf16)a.y; v[2] = (__bf16)a.z; v[3] = (__bf16)a.w;
    v[4] = (__bf16)b.x; v[5] = (__bf16)b.y; v[6] = (__bf16)b.z; v[7] = (__bf16)b.w;
    uint4 r;
    __builtin_memcpy(&r, &v, 16);
    return r;
}

// ---------------- kA: transpose Wglu/Wf -> bf16 + FiLM (wide grid) ----------------
__global__ __launch_bounds__(256) void kA(
    const float* __restrict__ Wglu, const float* __restrict__ Wf,
    const float* __restrict__ c, const float* __restrict__ W0,
    const float* __restrict__ b0, const float* __restrict__ alpha,
    const float* __restrict__ Wg, const float* __restrict__ bg,
    const float* __restrict__ Wb, const float* __restrict__ bb,
    unsigned short* __restrict__ WgluT, unsigned short* __restrict__ WfT,
    unsigned short* __restrict__ cfilm) {
    const int blk = blockIdx.x, tid = threadIdx.x;
    if (blk < 192) {
        __shared__ float ldsF[64 * 65];
        const float* src; unsigned short* dst; int tj, tk, srcld;
        if (blk < 128) { tj = blk >> 3; tk = blk & 7; src = Wglu; dst = WgluT; srcld = 1024; }
        else { int b2 = blk - 128; tj = b2 >> 3; tk = b2 & 7; src = Wf; dst = WfT; srcld = 512; }
#pragma unroll
        for (int rr = 0; rr < 16; ++rr) {
            int kl = (tid >> 6) + (rr << 2), jl = tid & 63;
            ldsF[kl * 65 + jl] = src[(size_t)(tk * 64 + kl) * srcld + tj * 64 + jl];
        }
        __syncthreads();
#pragma unroll
        for (int rr = 0; rr < 16; ++rr) {
            int jl = (tid >> 6) + (rr << 2), kl = tid & 63;
            dst[(size_t)(tj * 64 + jl) * 512 + tk * 64 + kl] = f2bf(ldsF[kl * 65 + jl]);
        }
    } else {
        int id = (blk - 192) * 256 + tid;
        int b = id >> 9, f = id & 511;
        const float* cb = c + b * 16;
        float d0 = 0.f, dg = 0.f, db = 0.f;
#pragma unroll
        for (int i = 0; i < 16; ++i) {
            float cv = cb[i];
            d0 += cv * W0[i * 512 + f];
            dg += cv * Wg[i * 512 + f];
            db += cv * Wb[i * 512 + f];
        }
        float pre = d0 + b0[f];
        float pr = pre >= 0.f ? pre : alpha[f] * pre;
        float v = pr * (dg + bg[f]) + (db + bb[f]);
        cfilm[id] = f2bf(v);
    }
}

// ---------------- k2: GLU GEMM (16x16x32), fused a*sigmoid(gate) ----------------
__global__ __launch_bounds__(256) void k2_glu(
    const unsigned short* __restrict__ cfilm, const unsigned short* __restrict__ WgluT,
    const float* __restrict__ bglu, unsigned short* __restrict__ cglu) {
    int wid = (blockIdx.x * 256 + threadIdx.x) >> 6;
    int l = threadIdx.x & 63;
    int tm = wid >> 5, tn = wid & 31;
    int row = tm * 16 + (l & 15);
    int col = tn * 16 + (l & 15);
    int kh = 8 * (l >> 4);
    f32x4 accA, accG;
#pragma unroll
    for (int i = 0; i < 4; ++i) { accA[i] = 0.f; accG[i] = 0.f; }
    const unsigned short* ap  = cfilm + row * 512 + kh;
    const unsigned short* bap = WgluT + col * 512 + kh;
    const unsigned short* bgp = WgluT + (512 + col) * 512 + kh;
#pragma unroll
    for (int kc = 0; kc < 16; ++kc) {
        bf16x8 a   = *(const bf16x8*)(ap  + kc * 32);
        bf16x8 ba  = *(const bf16x8*)(bap + kc * 32);
        bf16x8 bgt = *(const bf16x8*)(bgp + kc * 32);
        accA = __builtin_amdgcn_mfma_f32_16x16x32_bf16(a, ba,  accA, 0, 0, 0);
        accG = __builtin_amdgcn_mfma_f32_16x16x32_bf16(a, bgt, accG, 0, 0, 0);
    }
    float biasA = bglu[col], biasG = bglu[512 + col];
#pragma unroll
    for (int r = 0; r < 4; ++r) {
        float ga = accA[r] + biasA;
        float gg = accG[r] + biasG;
        float s = 1.f / (1.f + expf(-gg));
        int m = (l >> 4) * 4 + r;
        cglu[(tm * 16 + m) * 512 + col] = f2bf(ga * s);
    }
}

// ---------------- k3: Dense GEMM (16x16x32) + softsign -> filters bf16 ----------------
__global__ __launch_bounds__(256) void k3_filt(
    const unsigned short* __restrict__ cglu, const unsigned short* __restrict__ WfT,
    const float* __restrict__ bfv, unsigned short* __restrict__ hout) {
    int wid = (blockIdx.x * 256 + threadIdx.x) >> 6;
    int l = threadIdx.x & 63;
    int tm = wid >> 5, tn = wid & 31;
    int row = tm * 16 + (l & 15);
    int col = tn * 16 + (l & 15);
    int kh = 8 * (l >> 4);
    f32x4 acc;
#pragma unroll
    for (int i = 0; i < 4; ++i) acc[i] = 0.f;
    const unsigned short* ap = cglu + row * 512 + kh;
    const unsigned short* bp = WfT + col * 512 + kh;
#pragma unroll
    for (int kc = 0; kc < 16; ++kc) {
        bf16x8 a  = *(const bf16x8*)(ap + kc * 32);
        bf16x8 bv = *(const bf16x8*)(bp + kc * 32);
        acc = __builtin_amdgcn_mfma_f32_16x16x32_bf16(a, bv, acc, 0, 0, 0);
    }
    float bias = bfv[col];
#pragma unroll
    for (int r = 0; r < 4; ++r) {
        float z = acc[r] + bias;
        float h = z / (1.f + fabsf(z));
        int m = (l >> 4) * 4 + r;
        hout[(tm * 16 + m) * 512 + col] = f2bf(h);
    }
}

// ---------------- k7: MFMA FIR conv, single-shot blocks, TLP overlap ----------------
// Block = quarter batch (8192 outs), grid 2048, 5 blocks/CU (20 waves).
// 4 waves x 2 tiles(1024). No double-buffer: stage -> barrier -> compute -> store;
// overlap comes from 5 independent resident blocks at staggered phases.
// LDS: x tile 1088 units x 16B (XOR-swizzled)  [0,17408)
//      hr copies: 8 shifted copies of reversed h [17408,26752)  (stride 1168B)
//      hs (h row, 512 bf16)                      [26752,27776)
// B-fragment: vals[i] = h[16cc-16+q-8hl-i] = hrp[o0-16cc+i], hrp[t]=h[543-t],
// zero outside t in [32,544); o0 = 559-q+8hl; copy s=o0&7 -> aligned ds_read_b128.
__global__ __launch_bounds__(256, 5) void k7(
    const float* __restrict__ x, const unsigned short* __restrict__ hbf,
    float* __restrict__ y) {
    __shared__ __align__(16) unsigned char smem[27776];
    const int tid = threadIdx.x;
    // XCD swizzle (bijective on 2048): one batch's 4 blocks -> same XCD (x halo + h reuse)
    const int nb = blockIdx.x;
    const int virt = ((nb >> 5) << 5) + ((nb & 7) << 2) + ((nb >> 3) & 3);
    const int b = virt >> 2;
    const int n0 = (virt & 3) << 13;
    const float* xb = x + (size_t)b * 32768;
    unsigned short* hs = (unsigned short*)(smem + 26752);

    ((unsigned int*)hs)[tid] = ((const unsigned int*)(hbf + (size_t)b * 512))[tid];
    __syncthreads();

    // 8 shifted copies of reversed h, word-packed
    for (int e = tid; e < 8 * 292; e += 256) {
        int s = e / 292, w = e - s * 292;
        int j0 = 2 * w + s;
        unsigned int v0 = (j0 >= 32 && j0 < 544) ? hs[543 - j0] : 0u;
        unsigned int v1 = (j0 >= 31 && j0 < 543) ? hs[542 - j0] : 0u;
        ((unsigned int*)(smem + 17408))[e] = v0 | (v1 << 16);
    }

    // stage x window [n0-512, n0+8192) as bf16, XOR-swizzled
#pragma unroll
    for (int r2 = 0; r2 < 5; ++r2) {
        int slot = tid + (r2 << 8);
        if (slot < 1088) {
            int off = n0 + ((slot - 64) << 3);          // float offset from xb
            uint4 w4;
            if (off >= 0) {
                float4 a  = *(const float4*)(xb + off);
                float4 b2 = *(const float4*)(xb + off + 4);
                w4 = pack8n(a, b2);
            } else {
                w4 = make_uint4(0u, 0u, 0u, 0u);
            }
            *(uint4*)(smem + ((slot ^ ((slot >> 3) & 7)) << 4)) = w4;
        }
    }
    __syncthreads();

    const int w = tid >> 6, l = tid & 63;
    const int q = l & 31, hl = l >> 5;
    const int lq = 4 * q + hl;
    const int abase = 66 + (w << 8) + lq;               // A slot for cc=0, tile 0
    const int o0 = 559 - q + 8 * hl;
    const int s8 = o0 & 7;
    const unsigned char* hrb = smem + 17408 + s8 * 1168 + ((o0 - s8) << 1);

    f32x16 acc0, acc1;
#pragma unroll
    for (int i = 0; i < 16; ++i) { acc0[i] = 0.f; acc1[i] = 0.f; }
#pragma unroll
    for (int cc = 0; cc < 34; ++cc) {
        bf16x8 bfr = *(const bf16x8*)(hrb - (cc << 5));
        int a0 = abase - 2 * cc, a1 = a0 + 128;
        bf16x8 xa0 = *(const bf16x8*)(smem + ((a0 ^ ((a0 >> 3) & 7)) << 4));
        bf16x8 xa1 = *(const bf16x8*)(smem + ((a1 ^ ((a1 >> 3) & 7)) << 4));
        acc0 = __builtin_amdgcn_mfma_f32_32x32x16_bf16(xa0, bfr, acc0, 0, 0, 0);
        acc1 = __builtin_amdgcn_mfma_f32_32x32x16_bf16(xa1, bfr, acc1, 0, 0, 0);
    }
    // D layout: col = l&31, row m = (r&3) + 8*(r>>2) + 4*hl
    float* yb = y + (size_t)b * 32768 + n0 + (w << 11) + q;
#pragma unroll
    for (int r = 0; r < 16; ++r) {
        int m = (r & 3) + 8 * (r >> 2) + 4 * hl;
        yb[m << 5] = acc0[r];
        yb[1024 + (m << 5)] = acc1[r];
    }
}

extern "C" void kernel_launch(void* const* d_in, const int* in_sizes, int n_in,
                              void* d_out, int out_size, void* d_ws, size_t ws_size,
                              hipStream_t stream) {
    const float* x    = (const float*)d_in[0];
    const float* c    = (const float*)d_in[1];
    const float* W0   = (const float*)d_in[2];
    const float* b0   = (const float*)d_in[3];
    const float* al   = (const float*)d_in[4];
    const float* Wg   = (const float*)d_in[5];
    const float* bg   = (const float*)d_in[6];
    const float* Wb   = (const float*)d_in[7];
    const float* bb   = (const float*)d_in[8];
    const float* Wglu = (const float*)d_in[9];
    const float* bglu = (const float*)d_in[10];
    const float* Wf   = (const float*)d_in[11];
    const float* bf   = (const float*)d_in[12];
    float* y = (float*)d_out;

    char* ws = (char*)d_ws;
    unsigned short* cfilm = (unsigned short*)(ws);             // 512 KB
    unsigned short* WgluT = (unsigned short*)(ws + 524288);    // 1 MB
    unsigned short* WfT   = (unsigned short*)(ws + 1572864);   // 512 KB
    unsigned short* cglu  = (unsigned short*)(ws + 2097152);   // 512 KB
    unsigned short* hbf   = (unsigned short*)(ws + 2621440);   // 512 KB

    kA<<<dim3(1216), dim3(256), 0, stream>>>(Wglu, Wf, c, W0, b0, al, Wg, bg, Wb, bb,
                                             WgluT, WfT, cfilm);
    k2_glu<<<dim3(256), dim3(256), 0, stream>>>(cfilm, WgluT, bglu, cglu);
    k3_filt<<<dim3(256), dim3(256), 0, stream>>>(cglu, WfT, bf, hbf);
    k7<<<dim3(2048), dim3(256), 0, stream>>>(x, hbf, y);
}

// Round 9
// 49.178 us; speedup vs baseline: 1.0753x; 1.0753x over previous
//
#include <hip/hip_runtime.h>

// B=512 batches, MBS=32768 samples, F=512 taps, CD=16 cond dims.
// y[b,n] = sum_{t<512} h[b,t] * x[b,n-t]  (linear conv, zero history)

typedef float f32x16 __attribute__((ext_vector_type(16)));
typedef float f32x4  __attribute__((ext_vector_type(4)));
typedef __bf16 bf16x8 __attribute__((ext_vector_type(8)));

__device__ __forceinline__ unsigned short f2bf(float f) {
    unsigned int u = __float_as_uint(f);
    u += 0x7FFFu + ((u >> 16) & 1u);   // round-to-nearest-even
    return (unsigned short)(u >> 16);
}

__device__ __forceinline__ uint4 pack8n(float4 a, float4 b) {
    bf16x8 v;
    v[0] = (__bf16)a.x; v[1] = (__bf16)a.y; v[2] = (__bf16)a.z; v[3] = (__bf16)a.w;
    v[4] = (__bf16)b.x; v[5] = (__bf16)b.y; v[6] = (__bf16)b.z; v[7] = (__bf16)b.w;
    uint4 r;
    __builtin_memcpy(&r, &v, 16);
    return r;
}

// ---------------- kA: transpose Wglu/Wf -> bf16 + FiLM (wide grid) ----------------
__global__ __launch_bounds__(256) void kA(
    const float* __restrict__ Wglu, const float* __restrict__ Wf,
    const float* __restrict__ c, const float* __restrict__ W0,
    const float* __restrict__ b0, const float* __restrict__ alpha,
    const float* __restrict__ Wg, const float* __restrict__ bg,
    const float* __restrict__ Wb, const float* __restrict__ bb,
    unsigned short* __restrict__ WgluT, unsigned short* __restrict__ WfT,
    unsigned short* __restrict__ cfilm) {
    const int blk = blockIdx.x, tid = threadIdx.x;
    if (blk < 192) {
        __shared__ float ldsF[64 * 65];
        const float* src; unsigned short* dst; int tj, tk, srcld;
        if (blk < 128) { tj = blk >> 3; tk = blk & 7; src = Wglu; dst = WgluT; srcld = 1024; }
        else { int b2 = blk - 128; tj = b2 >> 3; tk = b2 & 7; src = Wf; dst = WfT; srcld = 512; }
#pragma unroll
        for (int rr = 0; rr < 16; ++rr) {
            int kl = (tid >> 6) + (rr << 2), jl = tid & 63;
            ldsF[kl * 65 + jl] = src[(size_t)(tk * 64 + kl) * srcld + tj * 64 + jl];
        }
        __syncthreads();
#pragma unroll
        for (int rr = 0; rr < 16; ++rr) {
            int jl = (tid >> 6) + (rr << 2), kl = tid & 63;
            dst[(size_t)(tj * 64 + jl) * 512 + tk * 64 + kl] = f2bf(ldsF[kl * 65 + jl]);
        }
    } else {
        int id = (blk - 192) * 256 + tid;
        int b = id >> 9, f = id & 511;
        const float* cb = c + b * 16;
        float d0 = 0.f, dg = 0.f, db = 0.f;
#pragma unroll
        for (int i = 0; i < 16; ++i) {
            float cv = cb[i];
            d0 += cv * W0[i * 512 + f];
            dg += cv * Wg[i * 512 + f];
            db += cv * Wb[i * 512 + f];
        }
        float pre = d0 + b0[f];
        float pr = pre >= 0.f ? pre : alpha[f] * pre;
        float v = pr * (dg + bg[f]) + (db + bb[f]);
        cfilm[id] = f2bf(v);
    }
}

// ---------------- k2: GLU GEMM (16x16x32), fused a*sigmoid(gate) ----------------
__global__ __launch_bounds__(256) void k2_glu(
    const unsigned short* __restrict__ cfilm, const unsigned short* __restrict__ WgluT,
    const float* __restrict__ bglu, unsigned short* __restrict__ cglu) {
    int wid = (blockIdx.x * 256 + threadIdx.x) >> 6;
    int l = threadIdx.x & 63;
    int tm = wid >> 5, tn = wid & 31;
    int row = tm * 16 + (l & 15);
    int col = tn * 16 + (l & 15);
    int kh = 8 * (l >> 4);
    f32x4 accA, accG;
#pragma unroll
    for (int i = 0; i < 4; ++i) { accA[i] = 0.f; accG[i] = 0.f; }
    const unsigned short* ap  = cfilm + row * 512 + kh;
    const unsigned short* bap = WgluT + col * 512 + kh;
    const unsigned short* bgp = WgluT + (512 + col) * 512 + kh;
#pragma unroll
    for (int kc = 0; kc < 16; ++kc) {
        bf16x8 a   = *(const bf16x8*)(ap  + kc * 32);
        bf16x8 ba  = *(const bf16x8*)(bap + kc * 32);
        bf16x8 bgt = *(const bf16x8*)(bgp + kc * 32);
        accA = __builtin_amdgcn_mfma_f32_16x16x32_bf16(a, ba,  accA, 0, 0, 0);
        accG = __builtin_amdgcn_mfma_f32_16x16x32_bf16(a, bgt, accG, 0, 0, 0);
    }
    float biasA = bglu[col], biasG = bglu[512 + col];
#pragma unroll
    for (int r = 0; r < 4; ++r) {
        float ga = accA[r] + biasA;
        float gg = accG[r] + biasG;
        float s = 1.f / (1.f + expf(-gg));
        int m = (l >> 4) * 4 + r;
        cglu[(tm * 16 + m) * 512 + col] = f2bf(ga * s);
    }
}

// ---------------- k3: Dense GEMM (16x16x32) + softsign -> filters bf16 ----------------
__global__ __launch_bounds__(256) void k3_filt(
    const unsigned short* __restrict__ cglu, const unsigned short* __restrict__ WfT,
    const float* __restrict__ bfv, unsigned short* __restrict__ hout) {
    int wid = (blockIdx.x * 256 + threadIdx.x) >> 6;
    int l = threadIdx.x & 63;
    int tm = wid >> 5, tn = wid & 31;
    int row = tm * 16 + (l & 15);
    int col = tn * 16 + (l & 15);
    int kh = 8 * (l >> 4);
    f32x4 acc;
#pragma unroll
    for (int i = 0; i < 4; ++i) acc[i] = 0.f;
    const unsigned short* ap = cglu + row * 512 + kh;
    const unsigned short* bp = WfT + col * 512 + kh;
#pragma unroll
    for (int kc = 0; kc < 16; ++kc) {
        bf16x8 a  = *(const bf16x8*)(ap + kc * 32);
        bf16x8 bv = *(const bf16x8*)(bp + kc * 32);
        acc = __builtin_amdgcn_mfma_f32_16x16x32_bf16(a, bv, acc, 0, 0, 0);
    }
    float bias = bfv[col];
#pragma unroll
    for (int r = 0; r < 4; ++r) {
        float z = acc[r] + bias;
        float h = z / (1.f + fabsf(z));
        int m = (l >> 4) * 4 + r;
        hout[(tm * 16 + m) * 512 + col] = f2bf(h);
    }
}

// ---------------- k5e: pipelined MFMA FIR conv, end-of-chunk staging write ----------------
// Block = 1 batch (grid 512, 2 blocks/CU). 4 waves x 2 tiles; 4 chunks of 8192 outs.
// Identical to k5 except the convert+ds_write of the next chunk's tile moved AFTER
// the second MFMA half-loop: loads get the full chunk (~4-5us) to land, removing the
// mid-chunk vmcnt stall.
// LDS: x dbuf 2 x 1088 units x 16B (XOR-swizzled) [0,34816)
//      hr copies: 8 shifted copies of reversed h   [34816,44160)  (stride 1168B)
//      hs (h row, 512 bf16)                        [44160,45184)
__global__ __launch_bounds__(256, 2) void k5e(
    const float* __restrict__ x, const unsigned short* __restrict__ hbf,
    float* __restrict__ y) {
    __shared__ __align__(16) unsigned char smem[45184];
    const int tid = threadIdx.x;
    const int b = blockIdx.x;
    const float* xb = x + (size_t)b * 32768;
    unsigned short* hs = (unsigned short*)(smem + 44160);

    ((unsigned int*)hs)[tid] = ((const unsigned int*)(hbf + (size_t)b * 512))[tid];
    __syncthreads();

    // 8 shifted copies of reversed h: cop[s][j] = hrp[j+s], word-packed
    for (int e = tid; e < 8 * 292; e += 256) {
        int s = e / 292, w = e - s * 292;
        int j0 = 2 * w + s;
        unsigned int v0 = (j0 >= 32 && j0 < 544) ? hs[543 - j0] : 0u;
        unsigned int v1 = (j0 >= 31 && j0 < 543) ? hs[542 - j0] : 0u;
        ((unsigned int*)(smem + 34816))[e] = v0 | (v1 << 16);
    }

    // prologue: stage chunk 0 window [-512, 8192) into buf0
#pragma unroll
    for (int r = 0; r < 5; ++r) {
        int slot = tid + (r << 8);
        if (slot < 1088) {
            int g = slot - 64;
            uint4 w4;
            if (g >= 0) {
                float4 a  = *(const float4*)(xb + g * 8);
                float4 b2 = *(const float4*)(xb + g * 8 + 4);
                w4 = pack8n(a, b2);
            } else {
                w4 = make_uint4(0u, 0u, 0u, 0u);
            }
            *(uint4*)(smem + ((slot ^ ((slot >> 3) & 7)) << 4)) = w4;
        }
    }
    __syncthreads();

    const int w = tid >> 6, l = tid & 63;
    const int q = l & 31, hl = l >> 5;
    const int lq = 4 * q + hl;
    const int abase = 66 + (w << 8) + lq;              // A slot for cc=0, tile 0
    const int o0 = 559 - q + 8 * hl;
    const int s8 = o0 & 7;
    const unsigned char* hrb = smem + 34816 + s8 * 1168 + ((o0 - s8) << 1);

    for (int c = 0; c < 4; ++c) {
        const unsigned char* wb = smem + ((c & 1) ? 17408 : 0);
        unsigned char* sb = smem + ((c & 1) ? 0 : 17408);
        float4 La0, La1, La2, La3, La4, Lb0, Lb1, Lb2, Lb3, Lb4;
        if (c < 3) {                                   // issue next-chunk loads
            const float* px = xb + (((c + 1) << 13) - 512);
            La0 = *(const float4*)(px + (tid << 3));           Lb0 = *(const float4*)(px + (tid << 3) + 4);
            La1 = *(const float4*)(px + ((tid + 256) << 3));   Lb1 = *(const float4*)(px + ((tid + 256) << 3) + 4);
            La2 = *(const float4*)(px + ((tid + 512) << 3));   Lb2 = *(const float4*)(px + ((tid + 512) << 3) + 4);
            La3 = *(const float4*)(px + ((tid + 768) << 3));   Lb3 = *(const float4*)(px + ((tid + 768) << 3) + 4);
            if (tid < 64) {
                La4 = *(const float4*)(px + ((tid + 1024) << 3));
                Lb4 = *(const float4*)(px + ((tid + 1024) << 3) + 4);
            }
        }
        f32x16 acc0, acc1;
#pragma unroll
        for (int i = 0; i < 16; ++i) { acc0[i] = 0.f; acc1[i] = 0.f; }
#pragma unroll
        for (int cc = 0; cc < 17; ++cc) {
            bf16x8 bfr = *(const bf16x8*)(hrb - (cc << 5));
            int a0 = abase - 2 * cc, a1 = a0 + 128;
            bf16x8 xa0 = *(const bf16x8*)(wb + ((a0 ^ ((a0 >> 3) & 7)) << 4));
            bf16x8 xa1 = *(const bf16x8*)(wb + ((a1 ^ ((a1 >> 3) & 7)) << 4));
            acc0 = __builtin_amdgcn_mfma_f32_32x32x16_bf16(xa0, bfr, acc0, 0, 0, 0);
            acc1 = __builtin_amdgcn_mfma_f32_32x32x16_bf16(xa1, bfr, acc1, 0, 0, 0);
        }
#pragma unroll
        for (int cc = 17; cc < 34; ++cc) {
            bf16x8 bfr = *(const bf16x8*)(hrb - (cc << 5));
            int a0 = abase - 2 * cc, a1 = a0 + 128;
            bf16x8 xa0 = *(const bf16x8*)(wb + ((a0 ^ ((a0 >> 3) & 7)) << 4));
            bf16x8 xa1 = *(const bf16x8*)(wb + ((a1 ^ ((a1 >> 3) & 7)) << 4));
            acc0 = __builtin_amdgcn_mfma_f32_32x32x16_bf16(xa0, bfr, acc0, 0, 0, 0);
            acc1 = __builtin_amdgcn_mfma_f32_32x32x16_bf16(xa1, bfr, acc1, 0, 0, 0);
        }
        if (c < 3) {                                   // convert + write staged tile (END of chunk)
            int s0 = tid;
            *(uint4*)(sb + ((s0 ^ ((s0 >> 3) & 7)) << 4)) = pack8n(La0, Lb0);
            int s1 = tid + 256;
            *(uint4*)(sb + ((s1 ^ ((s1 >> 3) & 7)) << 4)) = pack8n(La1, Lb1);
            int s2 = tid + 512;
            *(uint4*)(sb + ((s2 ^ ((s2 >> 3) & 7)) << 4)) = pack8n(La2, Lb2);
            int s3 = tid + 768;
            *(uint4*)(sb + ((s3 ^ ((s3 >> 3) & 7)) << 4)) = pack8n(La3, Lb3);
            if (tid < 64) {
                int s4 = tid + 1024;
                *(uint4*)(sb + ((s4 ^ ((s4 >> 3) & 7)) << 4)) = pack8n(La4, Lb4);
            }
        }
        // LDS writes visible to all waves before next chunk's reads; stores stay async
        asm volatile("s_waitcnt lgkmcnt(0)" ::: "memory");
        __builtin_amdgcn_s_barrier();
        __builtin_amdgcn_sched_barrier(0);
        // store chunk c (overlaps next iteration's loads/compute)
        float* yb = y + (size_t)b * 32768 + (c << 13) + (w << 11) + q;
#pragma unroll
        for (int r = 0; r < 16; ++r) {
            int m = (r & 3) + 8 * (r >> 2) + 4 * hl;   // D: col=l&31, row m
            yb[m << 5] = acc0[r];
            yb[1024 + (m << 5)] = acc1[r];
        }
    }
}

extern "C" void kernel_launch(void* const* d_in, const int* in_sizes, int n_in,
                              void* d_out, int out_size, void* d_ws, size_t ws_size,
                              hipStream_t stream) {
    const float* x    = (const float*)d_in[0];
    const float* c    = (const float*)d_in[1];
    const float* W0   = (const float*)d_in[2];
    const float* b0   = (const float*)d_in[3];
    const float* al   = (const float*)d_in[4];
    const float* Wg   = (const float*)d_in[5];
    const float* bg   = (const float*)d_in[6];
    const float* Wb   = (const float*)d_in[7];
    const float* bb   = (const float*)d_in[8];
    const float* Wglu = (const float*)d_in[9];
    const float* bglu = (const float*)d_in[10];
    const float* Wf   = (const float*)d_in[11];
    const float* bf   = (const float*)d_in[12];
    float* y = (float*)d_out;

    char* ws = (char*)d_ws;
    unsigned short* cfilm = (unsigned short*)(ws);             // 512 KB
    unsigned short* WgluT = (unsigned short*)(ws + 524288);    // 1 MB
    unsigned short* WfT   = (unsigned short*)(ws + 1572864);   // 512 KB
    unsigned short* cglu  = (unsigned short*)(ws + 2097152);   // 512 KB
    unsigned short* hbf   = (unsigned short*)(ws + 2621440);   // 512 KB

    kA<<<dim3(1216), dim3(256), 0, stream>>>(Wglu, Wf, c, W0, b0, al, Wg, bg, Wb, bb,
                                             WgluT, WfT, cfilm);
    k2_glu<<<dim3(256), dim3(256), 0, stream>>>(cfilm, WgluT, bglu, cglu);
    k3_filt<<<dim3(256), dim3(256), 0, stream>>>(cglu, WfT, bf, hbf);
    k5e<<<dim3(512), dim3(256), 0, stream>>>(x, hbf, y);
}